// Round 1
// baseline (802.848 us; speedup 1.0000x reference)
//
#include <hip/hip_runtime.h>

// DCNv4 3D — round 1: bf16 MFMA GEMMs + wave-per-(row,group) sampling core.
// N=2 D=H=W=32 C=128 G=8 Cg=16 K=27 OM_DIM=864. Output f32.

typedef __bf16 bf16;
typedef __bf16 bf16x8 __attribute__((ext_vector_type(8)));
typedef __bf16 bf16x4 __attribute__((ext_vector_type(4)));
typedef float  f32x4  __attribute__((ext_vector_type(4)));

#define NB 2
#define DD 32
#define HH 32
#define WW 32
#define CC 128
#define GG 8
#define CG 16
#define KPTS 27
#define LL (DD*HH*WW)     // 32768
#define MM (NB*LL)        // 65536
#define OMD 864
#define PXW (CC + OMD)    // 992

// ---------------- f32 -> bf16 conversion (vectorized x4) ----------------
__global__ __launch_bounds__(256) void cvt_f2b(const float* __restrict__ in,
                                               bf16* __restrict__ out, int n4) {
  int i = blockIdx.x * blockDim.x + threadIdx.x;
  if (i >= n4) return;
  float4 v = ((const float4*)in)[i];
  bf16x4 o;
  o[0] = (bf16)v.x; o[1] = (bf16)v.y; o[2] = (bf16)v.z; o[3] = (bf16)v.w;
  ((bf16x4*)out)[i] = o;
}

// ---------------- GEMM: out[M,ncols] = A[M,128] @ B[ncols,128]^T + bias --
// Block: 256 thr = 4 waves. Tile: 64 rows x 32 cols. Wave w owns rows
// [rowBase+w*16, +16). Per wave: two 16x16 acc tiles, K=128 in 4 MFMA steps.
// A-frag: lane holds A[row=l&15][k=(l>>4)*8 + j]  (16B contiguous load)
// B-frag: lane holds B^T[col=l&15][k=(l>>4)*8 + j]
// D: D[row=(l>>4)*4+i][col=l&15]  (measured layout, learn_hip m89)
template<bool OUTF32>
__global__ __launch_bounds__(256) void gemm_k128(
    const bf16* __restrict__ A, const bf16* __restrict__ B,
    const float* __restrict__ bias_lo, const float* __restrict__ bias_hi,
    void* __restrict__ outp, int ncols) {
  const int w    = threadIdx.x >> 6;
  const int lane = threadIdx.x & 63;
  const int colBase = blockIdx.x * 32;
  const int rowBase = blockIdx.y * 64 + w * 16;
  const int r  = lane & 15;
  const int kg = lane >> 4;
  const bf16* Ap = A + (size_t)(rowBase + r) * CC + kg * 8;
  const bf16* Bp = B + (size_t)(colBase + r) * CC + kg * 8;
  f32x4 acc0 = {0.f, 0.f, 0.f, 0.f};
  f32x4 acc1 = {0.f, 0.f, 0.f, 0.f};
#pragma unroll
  for (int kk = 0; kk < 4; ++kk) {
    bf16x8 a  = *(const bf16x8*)(Ap + kk * 32);
    bf16x8 b0 = *(const bf16x8*)(Bp + kk * 32);
    bf16x8 b1 = *(const bf16x8*)(Bp + 16 * CC + kk * 32);
    acc0 = __builtin_amdgcn_mfma_f32_16x16x32_bf16(a, b0, acc0, 0, 0, 0);
    acc1 = __builtin_amdgcn_mfma_f32_16x16x32_bf16(a, b1, acc1, 0, 0, 0);
  }
  const int c0 = colBase + r;
  const int c1 = c0 + 16;
  const float bv0 = (c0 < CC) ? bias_lo[c0] : bias_hi[c0 - CC];
  const float bv1 = (c1 < CC) ? bias_lo[c1] : bias_hi[c1 - CC];
  const int drow = rowBase + kg * 4;
#pragma unroll
  for (int i = 0; i < 4; ++i) {
    float v0 = acc0[i] + bv0;
    float v1 = acc1[i] + bv1;
    size_t ro = (size_t)(drow + i) * ncols;
    if (OUTF32) {
      ((float*)outp)[ro + c0] = v0;
      ((float*)outp)[ro + c1] = v1;
    } else {
      ((bf16*)outp)[ro + c0] = (bf16)v0;
      ((bf16*)outp)[ro + c1] = (bf16)v1;
    }
  }
}

// ---------------- DCNv4 sampling core ----------------
// pxo row layout: [0,128) = value features x; [128,992) = om (per group g:
// 81 offsets (k-major, d/h/w) then 27 masks at g*108).
// One wave per (row, g). lane = hi(k-subgroup, 8) * 8 + lo(channel-pair, 8).
// k = kit*8 + hi over 4 iters (k<27). Butterfly-reduce over hi at the end.
__global__ __launch_bounds__(256) void dcn_core(const bf16* __restrict__ pxo,
                                                bf16* __restrict__ y) {
  const int wid  = blockIdx.x * 4 + (threadIdx.x >> 6);
  const int lane = threadIdx.x & 63;
  const int row  = wid >> 3;
  const int g    = wid & 7;
  const int l    = row & (LL - 1);
  const int nbase = row & ~(LL - 1);   // n * L
  const int ldz = l >> 10;
  const int lhy = (l >> 5) & 31;
  const int lwx = l & 31;
  const int lo = lane & 7;
  const int hi = lane >> 3;
  const bf16* om = pxo + (size_t)row * PXW + CC + g * 108;
  const bf16* xg = pxo + g * CG + lo * 2;
  float acc0 = 0.f, acc1 = 0.f;
#pragma unroll
  for (int kit = 0; kit < 4; ++kit) {
    int k = kit * 8 + hi;
    if (k < KPTS) {
      float od = (float)om[k * 3 + 0];
      float oh = (float)om[k * 3 + 1];
      float ow = (float)om[k * 3 + 2];
      float m  = (float)om[81 + k];
      int kd = k / 9, kh = (k / 3) % 3, kw = k % 3;
      float pd = (float)(ldz + kd - 1) + od;
      float ph = (float)(lhy + kh - 1) + oh;
      float pw = (float)(lwx + kw - 1) + ow;
      float fd = floorf(pd), fh = floorf(ph), fw = floorf(pw);
      float td = pd - fd, th = ph - fh, tw = pw - fw;
      int id = (int)fd, ih = (int)fh, iw = (int)fw;
#pragma unroll
      for (int c = 0; c < 8; ++c) {
        int cz = (c >> 2) & 1, cy = (c >> 1) & 1, cx = c & 1;
        int cd = id + cz, chh = ih + cy, cww = iw + cx;
        float wgt = (cz ? td : 1.f - td) * (cy ? th : 1.f - th) *
                    (cx ? tw : 1.f - tw) * m;
        if ((unsigned)cd < DD && (unsigned)chh < HH && (unsigned)cww < WW) {
          int flat = (cd * HH + chh) * WW + cww;
          unsigned u = *(const unsigned*)(xg + (size_t)(nbase + flat) * PXW);
          float v0 = __uint_as_float(u << 16);
          float v1 = __uint_as_float(u & 0xffff0000u);
          acc0 += wgt * v0;
          acc1 += wgt * v1;
        }
      }
    }
  }
#pragma unroll
  for (int off = 8; off < 64; off <<= 1) {
    acc0 += __shfl_xor(acc0, off);
    acc1 += __shfl_xor(acc1, off);
  }
  if (hi == 0) {
    bf16* yp = y + (size_t)row * CC + g * CG + lo * 2;
    bf16x4 dummy;  // unused; keep stores simple
    yp[0] = (bf16)acc0;
    yp[1] = (bf16)acc1;
  }
}

extern "C" void kernel_launch(void* const* d_in, const int* in_sizes, int n_in,
                              void* d_out, int out_size, void* d_ws, size_t ws_size,
                              hipStream_t stream) {
  const float* f_in      = (const float*)d_in[0];  // [N,D,H,W,C]
  const float* value_w   = (const float*)d_in[1];  // [128,128]
  const float* value_b   = (const float*)d_in[2];  // [128]
  const float* offmask_w = (const float*)d_in[3];  // [864,128]
  const float* offmask_b = (const float*)d_in[4];  // [864]
  const float* out_w     = (const float*)d_in[5];  // [128,128]
  const float* out_b     = (const float*)d_in[6];  // [128]
  float* out = (float*)d_out;

  // ws layout (bf16 elements). Total ≈ 147 MB.
  bf16* xb   = (bf16*)d_ws;                       // [M,128]   input cast
  bf16* wcat = xb + (size_t)MM * CC;              // [992,128] value_w ++ offmask_w
  bf16* wout = wcat + (size_t)PXW * CC;           // [128,128]
  bf16* pxo  = wout + (size_t)CC * CC;            // [M,992]   x ++ om
  bf16* y    = xb;                                // [M,128]   aliases xb (xb dead after proj GEMM)

  int n4;
  n4 = MM * CC / 4;
  cvt_f2b<<<(n4 + 255) / 256, 256, 0, stream>>>(f_in, xb, n4);
  n4 = CC * CC / 4;
  cvt_f2b<<<(n4 + 255) / 256, 256, 0, stream>>>(value_w, wcat, n4);
  n4 = OMD * CC / 4;
  cvt_f2b<<<(n4 + 255) / 256, 256, 0, stream>>>(offmask_w, wcat + (size_t)CC * CC, n4);
  n4 = CC * CC / 4;
  cvt_f2b<<<(n4 + 255) / 256, 256, 0, stream>>>(out_w, wout, n4);

  // proj GEMM: [M,992] = xb @ wcat^T + (value_b ++ offmask_b), bf16 out
  dim3 g1(PXW / 32, MM / 64);
  gemm_k128<false><<<g1, dim3(256), 0, stream>>>(xb, wcat, value_b, offmask_b,
                                                 (void*)pxo, PXW);
  // sampling core: y[M,128] bf16
  dcn_core<<<MM * GG / 4, dim3(256), 0, stream>>>(pxo, y);
  // out GEMM: d_out[M,128] f32 = y @ out_w^T + out_b
  dim3 g2(CC / 32, MM / 64);
  gemm_k128<true><<<g2, dim3(256), 0, stream>>>(y, wout, out_b, nullptr,
                                                (void*)out, CC);
}

// Round 2
// 421.514 us; speedup vs baseline: 1.9047x; 1.9047x over previous
//
#include <hip/hip_runtime.h>

// DCNv4 3D — round 2:
//  * dcn_core v2: lane=(k-slot x chan-half), 16B gathers, per-dim folded
//    weights/validity, 32-bit addressing, straight-line (no k loop).
//  * gemm v2: A-fragments register-cached, block loops all col-tiles;
//    input f32->bf16 fused into proj GEMM A-load.

typedef __bf16 bf16;
typedef __bf16 bf16x8 __attribute__((ext_vector_type(8)));
typedef __bf16 bf16x4 __attribute__((ext_vector_type(4)));
typedef float  f32x4  __attribute__((ext_vector_type(4)));
typedef float  f32x2  __attribute__((ext_vector_type(2)));

#define NB 2
#define DD 32
#define HH 32
#define WW 32
#define CC 128
#define GG 8
#define CG 16
#define KPTS 27
#define LL (DD*HH*WW)     // 32768
#define MM (NB*LL)        // 65536
#define OMD 864
#define PXW (CC + OMD)    // 992

// byte strides inside pxo (bf16)
#define ROWB (PXW*2)          // 1984 bytes per flat-position step
#define YB   (WW*ROWB)        // 63488
#define ZB   (HH*WW*ROWB)     // 2031616

// ---------------- f32 -> bf16 conversion (weights only) -----------------
__global__ __launch_bounds__(256) void cvt_f2b(const float* __restrict__ in,
                                               bf16* __restrict__ out, int n4) {
  int i = blockIdx.x * blockDim.x + threadIdx.x;
  if (i >= n4) return;
  float4 v = ((const float4*)in)[i];
  bf16x4 o;
  o[0] = (bf16)v.x; o[1] = (bf16)v.y; o[2] = (bf16)v.z; o[3] = (bf16)v.w;
  ((bf16x4*)out)[i] = o;
}

// ---------------- GEMM: out[M,NCOLS] = A[M,128] @ B[NCOLS,128]^T + bias --
// Block = 256 thr = 4 waves; block owns 64 rows (wave w: rows +w*16).
// A-fragments cached in registers; loop over NCOLS/32 col-tiles.
// A-frag: lane holds A[row=l&15][k=(l>>4)*8+j]; D: row=(l>>4)*4+i, col=l&15.
template<bool AF32, bool OUTF32, int NCOLS>
__global__ __launch_bounds__(256) void gemm_k128(
    const void* __restrict__ Ain, const bf16* __restrict__ B,
    const float* __restrict__ bias_lo, const float* __restrict__ bias_hi,
    void* __restrict__ outp) {
  const int w    = threadIdx.x >> 6;
  const int lane = threadIdx.x & 63;
  const int rowBase = blockIdx.x * 64 + w * 16;
  const int r  = lane & 15;
  const int kg = lane >> 4;

  bf16x8 a[4];
  if (AF32) {
    const float* A = (const float*)Ain + (size_t)(rowBase + r) * CC + kg * 8;
#pragma unroll
    for (int kk = 0; kk < 4; ++kk) {
      float4 lo = *(const float4*)(A + kk * 32);
      float4 hi = *(const float4*)(A + kk * 32 + 4);
      bf16x8 t;
      t[0] = (bf16)lo.x; t[1] = (bf16)lo.y; t[2] = (bf16)lo.z; t[3] = (bf16)lo.w;
      t[4] = (bf16)hi.x; t[5] = (bf16)hi.y; t[6] = (bf16)hi.z; t[7] = (bf16)hi.w;
      a[kk] = t;
    }
  } else {
    const bf16* A = (const bf16*)Ain + (size_t)(rowBase + r) * CC + kg * 8;
#pragma unroll
    for (int kk = 0; kk < 4; ++kk) a[kk] = *(const bf16x8*)(A + kk * 32);
  }

  for (int ct = 0; ct < NCOLS / 32; ++ct) {
    const int colBase = ct * 32;
    const bf16* Bp = B + (unsigned)(colBase + r) * CC + kg * 8;
    f32x4 acc0 = {0.f, 0.f, 0.f, 0.f};
    f32x4 acc1 = {0.f, 0.f, 0.f, 0.f};
#pragma unroll
    for (int kk = 0; kk < 4; ++kk) {
      bf16x8 b0 = *(const bf16x8*)(Bp + kk * 32);
      bf16x8 b1 = *(const bf16x8*)(Bp + 16 * CC + kk * 32);
      acc0 = __builtin_amdgcn_mfma_f32_16x16x32_bf16(a[kk], b0, acc0, 0, 0, 0);
      acc1 = __builtin_amdgcn_mfma_f32_16x16x32_bf16(a[kk], b1, acc1, 0, 0, 0);
    }
    const int c0 = colBase + r;
    const int c1 = c0 + 16;
    const float bv0 = (c0 < CC) ? bias_lo[c0] : bias_hi[c0 - CC];
    const float bv1 = (c1 < CC) ? bias_lo[c1] : bias_hi[c1 - CC];
    const int drow = rowBase + kg * 4;
#pragma unroll
    for (int i = 0; i < 4; ++i) {
      float v0 = acc0[i] + bv0;
      float v1 = acc1[i] + bv1;
      unsigned ro = (unsigned)(drow + i) * NCOLS;
      if (OUTF32) {
        ((float*)outp)[ro + c0] = v0;
        ((float*)outp)[ro + c1] = v1;
      } else {
        ((bf16*)outp)[ro + c0] = (bf16)v0;
        ((bf16*)outp)[ro + c1] = (bf16)v1;
      }
    }
  }
}

// ---------------- DCNv4 sampling core v2 ----------------
// One wave per (row, g). lane = ks*2 + ch; ks = k-slot (0..31, 27 active),
// ch = channel half (8 channels, 16B per gather).
// Per-dim weights carry mask + validity; per-dim clamped byte offsets make
// each corner address a single v_add3. Butterfly-reduce over ks at the end.
__device__ __forceinline__ f32x2 bpair(unsigned u) {
  f32x2 r;
  r[0] = __uint_as_float(u << 16);
  r[1] = __uint_as_float(u & 0xffff0000u);
  return r;
}

__global__ __launch_bounds__(256) void dcn_core(const bf16* __restrict__ pxo,
                                                bf16* __restrict__ y) {
  const int wid  = blockIdx.x * 4 + (threadIdx.x >> 6);
  const int lane = threadIdx.x & 63;
  const int row  = wid >> 3;
  const int g    = wid & 7;
  const int ks   = lane >> 1;
  const int ch   = lane & 1;
  const int l    = row & (LL - 1);
  const int nb   = row >> 15;          // batch (LL = 2^15)
  const int ldz  = l >> 10;
  const int lhy  = (l >> 5) & 31;
  const int lwx  = l & 31;

  // per-lane k (clamped; inactive lanes get weight 0 via m)
  const int kc = (ks < KPTS) ? ks : KPTS - 1;
  const int kd = kc / 9, kh = (kc / 3) % 3, kw = kc % 3;

  const bf16* om = pxo + (unsigned)row * PXW + CC + g * 108;
  float od = (float)om[kc * 3 + 0];
  float oh = (float)om[kc * 3 + 1];
  float ow = (float)om[kc * 3 + 2];
  float m  = (ks < KPTS) ? (float)om[81 + kc] : 0.f;

  float pd = (float)(ldz + kd - 1) + od;
  float ph = (float)(lhy + kh - 1) + oh;
  float pw = (float)(lwx + kw - 1) + ow;
  float fd = floorf(pd), fh = floorf(ph), fw = floorf(pw);
  float td = pd - fd,    th = ph - fh,    tw = pw - fw;
  int   id = (int)fd,    ih = (int)fh,    iw = (int)fw;

  // per-dim weights with validity (and mask folded into z-dim)
  float wz0 = ((unsigned)id        < DD) ? (1.f - td) * m : 0.f;
  float wz1 = ((unsigned)(id + 1)  < DD) ? td * m         : 0.f;
  float wy0 = ((unsigned)ih        < HH) ? (1.f - th)     : 0.f;
  float wy1 = ((unsigned)(ih + 1)  < HH) ? th             : 0.f;
  float wx0 = ((unsigned)iw        < WW) ? (1.f - tw)     : 0.f;
  float wx1 = ((unsigned)(iw + 1)  < WW) ? tw             : 0.f;

  // per-dim clamped byte offsets (clamp keeps zero-weight reads in-bounds)
  const int zc0 = min(max(id,     0), DD - 1) * ZB;
  const int zc1 = min(max(id + 1, 0), DD - 1) * ZB;
  const int yc0 = min(max(ih,     0), HH - 1) * YB;
  const int yc1 = min(max(ih + 1, 0), HH - 1) * YB;
  const int xc0 = min(max(iw,     0), WW - 1) * ROWB + ch * 16;
  const int xc1 = min(max(iw + 1, 0), WW - 1) * ROWB + ch * 16;

  // wave-uniform base: pxo + batch offset + group channel offset (bytes)
  const int boff = __builtin_amdgcn_readfirstlane(nb * (LL * ROWB) + g * (CG * 2));
  const char* basep = (const char*)pxo + boff;

  uint4 q[8];
  float wg[8];
#pragma unroll
  for (int c = 0; c < 8; ++c) {
    const int cz = (c >> 2) & 1, cy = (c >> 1) & 1, cx = c & 1;
    const int voff = (cz ? zc1 : zc0) + (cy ? yc1 : yc0) + (cx ? xc1 : xc0);
    wg[c] = (cz ? wz1 : wz0) * (cy ? wy1 : wy0) * (cx ? wx1 : wx0);
    q[c] = *(const uint4*)(basep + voff);
  }

  f32x2 a0 = {0.f, 0.f}, a1 = {0.f, 0.f}, a2 = {0.f, 0.f}, a3 = {0.f, 0.f};
#pragma unroll
  for (int c = 0; c < 8; ++c) {
    f32x2 w2; w2[0] = wg[c]; w2[1] = wg[c];
    a0 += bpair(q[c].x) * w2;
    a1 += bpair(q[c].y) * w2;
    a2 += bpair(q[c].z) * w2;
    a3 += bpair(q[c].w) * w2;
  }

  // butterfly reduce over ks (lane bits 1..5)
#pragma unroll
  for (int msk = 2; msk <= 32; msk <<= 1) {
    a0[0] += __shfl_xor(a0[0], msk, 64); a0[1] += __shfl_xor(a0[1], msk, 64);
    a1[0] += __shfl_xor(a1[0], msk, 64); a1[1] += __shfl_xor(a1[1], msk, 64);
    a2[0] += __shfl_xor(a2[0], msk, 64); a2[1] += __shfl_xor(a2[1], msk, 64);
    a3[0] += __shfl_xor(a3[0], msk, 64); a3[1] += __shfl_xor(a3[1], msk, 64);
  }

  if (ks == 0) {
    bf16x8 o;
    o[0] = (bf16)a0[0]; o[1] = (bf16)a0[1];
    o[2] = (bf16)a1[0]; o[3] = (bf16)a1[1];
    o[4] = (bf16)a2[0]; o[5] = (bf16)a2[1];
    o[6] = (bf16)a3[0]; o[7] = (bf16)a3[1];
    *(bf16x8*)(y + (unsigned)row * CC + g * CG + ch * 8) = o;
  }
}

extern "C" void kernel_launch(void* const* d_in, const int* in_sizes, int n_in,
                              void* d_out, int out_size, void* d_ws, size_t ws_size,
                              hipStream_t stream) {
  const float* f_in      = (const float*)d_in[0];  // [N,D,H,W,C] f32
  const float* value_w   = (const float*)d_in[1];  // [128,128]
  const float* value_b   = (const float*)d_in[2];  // [128]
  const float* offmask_w = (const float*)d_in[3];  // [864,128]
  const float* offmask_b = (const float*)d_in[4];  // [864]
  const float* out_w     = (const float*)d_in[5];  // [128,128]
  const float* out_b     = (const float*)d_in[6];  // [128]
  float* out = (float*)d_out;

  // ws layout (bf16): wcat[992,128] | wout[128,128] | pxo[M,992] | y[M,128]
  bf16* wcat = (bf16*)d_ws;
  bf16* wout = wcat + (size_t)PXW * CC;
  bf16* pxo  = wout + (size_t)CC * CC;
  bf16* y    = pxo + (size_t)MM * PXW;

  int n4;
  n4 = PXW * CC / 4;
  cvt_f2b<<<(n4 + 255) / 256, 256, 0, stream>>>(value_w, wcat, CC * CC / 4);
  cvt_f2b<<<(OMD * CC / 4 + 255) / 256, 256, 0, stream>>>(
      offmask_w, wcat + (size_t)CC * CC, OMD * CC / 4);
  cvt_f2b<<<(CC * CC / 4 + 255) / 256, 256, 0, stream>>>(out_w, wout, CC * CC / 4);

  // proj GEMM: pxo[M,992] = f_in @ wcat^T + (value_b ++ offmask_b)  (A = f32)
  gemm_k128<true, false, PXW><<<MM / 64, dim3(256), 0, stream>>>(
      f_in, wcat, value_b, offmask_b, (void*)pxo);
  // sampling core: y[M,128] bf16
  dcn_core<<<MM * GG / 4, dim3(256), 0, stream>>>(pxo, y);
  // out GEMM: d_out[M,128] f32 = y @ wout^T + out_b
  gemm_k128<false, true, CC><<<MM / 64, dim3(256), 0, stream>>>(
      y, wout, out_b, out_b, (void*)out);
}